// Round 14
// baseline (1328.217 us; speedup 1.0000x reference)
//
#include <hip/hip_runtime.h>

#define DIM    128
#define K      256
#define NPTS   32768
#define NALL   (8*32768)
#define ITERS  10
#define FT     64
#define NB     256
#define WMARG  6.0f
#define CAPP   48

typedef short bf16x8 __attribute__((ext_vector_type(8)));
typedef float f32x4  __attribute__((ext_vector_type(4)));
typedef unsigned long long u64;

__device__ __forceinline__ unsigned short bf16_rne(float f) {
    unsigned int u = __float_as_uint(f);
    unsigned int r = u + 0x7fffu + ((u >> 16) & 1u);
    return (unsigned short)(r >> 16);
}
__device__ __forceinline__ float bf16_to_f(unsigned short h) {
    return __uint_as_float(((unsigned int)h) << 16);
}

// ---- agent-scope (L3-coherent, XCD-L2-bypassing) relaxed atomics ----
__device__ __forceinline__ u64 ald64(const void* p) {
    return __hip_atomic_load((const u64*)p, __ATOMIC_RELAXED, __HIP_MEMORY_SCOPE_AGENT);
}
__device__ __forceinline__ float ald_f(const float* p) {
    return __hip_atomic_load(p, __ATOMIC_RELAXED, __HIP_MEMORY_SCOPE_AGENT);
}
__device__ __forceinline__ float4 ald_f4(const float* p) {
    u64 a = ald64(p), b = ald64(p + 2);
    float4 r;
    r.x = __uint_as_float((unsigned)a); r.y = __uint_as_float((unsigned)(a >> 32));
    r.z = __uint_as_float((unsigned)b); r.w = __uint_as_float((unsigned)(b >> 32));
    return r;
}
__device__ __forceinline__ uint4 ald_u4(const void* p) {
    u64 a = ald64(p), b = ald64((const char*)p + 8);
    uint4 r;
    r.x = (unsigned)a; r.y = (unsigned)(a >> 32);
    r.z = (unsigned)b; r.w = (unsigned)(b >> 32);
    return r;
}
__device__ __forceinline__ void ast_f(float* p, float v) {
    __hip_atomic_store(p, v, __ATOMIC_RELAXED, __HIP_MEMORY_SCOPE_AGENT);
}
__device__ __forceinline__ void ast_u16(unsigned short* p, unsigned short v) {
    __hip_atomic_store(p, v, __ATOMIC_RELAXED, __HIP_MEMORY_SCOPE_AGENT);
}
__device__ __forceinline__ void ast_u8(unsigned char* p, unsigned char v) {
    __hip_atomic_store(p, v, __ATOMIC_RELAXED, __HIP_MEMORY_SCOPE_AGENT);
}

// numpy pairwise sum of squares, n=128, SSE2 path (scalar loads)
__device__ __forceinline__ float np_sumsq128(const float* p, int stride) {
    #pragma clang fp contract(off)
    float c[8];
    #pragma unroll
    for (int j = 0; j < 8; ++j) { float x = p[j*stride]; c[j] = x*x; }
    #pragma unroll
    for (int t = 1; t < 16; ++t)
        #pragma unroll
        for (int j = 0; j < 8; ++j) { float x = p[(8*t+j)*stride]; c[j] = c[j] + x*x; }
    float v0 = c[0] + c[4];
    float v1 = c[1] + c[5];
    float v2 = c[2] + c[6];
    float v3 = c[3] + c[7];
    return (v0 + v2) + (v1 + v3);
}

// same tree, float4 loads (identical arithmetic order -> identical bits)
__device__ __forceinline__ float np_sumsq128_f4(const float* p) {
    #pragma clang fp contract(off)
    float c[8];
    {
        float4 a = *(const float4*)p, b = *(const float4*)(p + 4);
        c[0]=a.x*a.x; c[1]=a.y*a.y; c[2]=a.z*a.z; c[3]=a.w*a.w;
        c[4]=b.x*b.x; c[5]=b.y*b.y; c[6]=b.z*b.z; c[7]=b.w*b.w;
    }
    #pragma unroll
    for (int t = 1; t < 16; ++t) {
        float4 a = *(const float4*)(p + 8*t), b = *(const float4*)(p + 8*t + 4);
        c[0]=c[0]+a.x*a.x; c[1]=c[1]+a.y*a.y; c[2]=c[2]+a.z*a.z; c[3]=c[3]+a.w*a.w;
        c[4]=c[4]+b.x*b.x; c[5]=c[5]+b.y*b.y; c[6]=c[6]+b.z*b.z; c[7]=c[7]+b.w*b.w;
    }
    float v0 = c[0] + c[4];
    float v1 = c[1] + c[5];
    float v2 = c[2] + c[6];
    float v3 = c[3] + c[7];
    return (v0 + v2) + (v1 + v3);
}

// ---------------- init ----------------
__global__ __launch_bounds__(DIM) void k_init(
    const float* __restrict__ x0, float* __restrict__ centers,
    unsigned short* __restrict__ cbfg, float* __restrict__ csqg,
    unsigned int* __restrict__ arrive)
{
    __shared__ float rowv[DIM];
    const int k = blockIdx.x, d = threadIdx.x;
    if (k == 0 && d == 0) *arrive = 0u;
    float v = x0[(size_t)k*DIM + d];
    centers[(size_t)k*DIM + d] = v;
    cbfg[(size_t)k*DIM + d] = bf16_rne(v);
    rowv[d] = v;
    __syncthreads();
    if (d == 0) csqg[k] = np_sumsq128(rowv, 1);
}

// ---------------- LDS union ----------------
struct ScreenSM {
    float          xf[128][132];
    unsigned short cbf[256][136];
    float          csqL[K];
    float          xsqL[128];
    unsigned int   pcnt[128];
    unsigned char  plist[128][CAPP];
    unsigned int   smink[4][128];
    unsigned char  sminn[4][128];
};
struct SegSM {
    int   nlist[NPTS];
    int   tsum[8];
    float rowv[DIM];
};
union LoopSM { ScreenSM s; SegSM g; };

// grid barrier: NO fences. All cross-block data moves via agent-scope atomics
// (L3-coherent); store completion is guaranteed by the compiler's
// s_waitcnt vmcnt(0) before each s_barrier (__syncthreads).
__device__ __forceinline__ void gbar(unsigned int* arrive, unsigned int target) {
    __syncthreads();
    if (threadIdx.x == 0) {
        __hip_atomic_fetch_add(arrive, 1u, __ATOMIC_RELAXED, __HIP_MEMORY_SCOPE_AGENT);
        while (__hip_atomic_load(arrive, __ATOMIC_RELAXED, __HIP_MEMORY_SCOPE_AGENT) < target)
            __builtin_amdgcn_s_sleep(8);
    }
    __syncthreads();
}

// ---------------- fold macros (exact np.add.at ascending-n left-fold) ----------------
#define LOADL(vv, t0) do {                                                  \
    int base_ = (t0)*FT;                                                    \
    int nn_[FT];                                                            \
    _Pragma("unroll")                                                       \
    for (int j = 0; j < FT; ++j) {                                          \
        int idx_ = base_ + j;                                               \
        nn_[j] = sm.g.nlist[idx_ < L ? idx_ : 0];                           \
    }                                                                       \
    _Pragma("unroll")                                                       \
    for (int j = 0; j < FT; ++j) vv[j] = x0[(size_t)nn_[j]*DIM + d];        \
} while (0)

#define FOLDL(vv, t0) do {                                                  \
    int rem_ = L - (t0)*FT;                                                 \
    if (rem_ >= FT) {                                                       \
        _Pragma("unroll")                                                   \
        for (int j = 0; j < FT; ++j) s = s + vv[j];                         \
    } else if (rem_ > 0) {                                                  \
        _Pragma("unroll")                                                   \
        for (int j = 0; j < FT; ++j) { float t_ = s + vv[j]; s = (j < rem_) ? t_ : s; } \
    }                                                                       \
} while (0)

// ---------------- fused 10-iteration kmeans + makeM ----------------
__global__ __launch_bounds__(512, 1) void k_all(
    const float* __restrict__ x0, const float* __restrict__ W,
    float* centers, unsigned char* assignv,
    unsigned short* cbfg, float* csqg,
    unsigned short* Mh, unsigned short* Ml, float* out_centers,
    unsigned int* arrive)
{
    __shared__ LoopSM sm;
    const int tid = threadIdx.x, lane = tid & 63, w = tid >> 6;
    const int bid = blockIdx.x;
    const int g = lane >> 4, fr = lane & 15;
    unsigned int tgt = 0;

    for (int it = 0; it < ITERS; ++it) {
        // ================= screen phase =================
        if (tid < 128) sm.s.pcnt[tid] = 0u;
        {
            #pragma unroll
            for (int i = 0; i < 8; ++i) {
                int idx = i*512 + tid;              // uint4 index: 8 ushorts each
                int row = idx >> 4, c8 = idx & 15;
                *(uint4*)&sm.s.cbf[row][c8*8] = ald_u4(cbfg + (size_t)idx*8);
            }
        }
        {
            const float4* x4 = (const float4*)x0 + (size_t)bid*128*32;
            #pragma unroll
            for (int i = 0; i < 8; ++i) {
                int idx = i*512 + tid;
                int row = idx >> 5, c4 = idx & 31;
                *(float4*)&sm.s.xf[row][c4*4] = x4[idx];   // normal cached load
            }
        }
        __syncthreads();

        if (tid < 256) sm.s.csqL[tid] = ald_f(&csqg[tid]);
        if (tid < 128) sm.s.xsqL[tid] = np_sumsq128_f4(&sm.s.xf[tid][0]);
        __syncthreads();

        bf16x8 ah[4];
        #pragma unroll
        for (int ks = 0; ks < 4; ++ks) {
            const float* xp = &sm.s.xf[w*16 + fr][ks*32 + g*8];
            float4 a0 = *(const float4*)xp;
            float4 a1 = *(const float4*)(xp + 4);
            bf16x8 t;
            t[0] = (short)bf16_rne(a0.x); t[1] = (short)bf16_rne(a0.y);
            t[2] = (short)bf16_rne(a0.z); t[3] = (short)bf16_rne(a0.w);
            t[4] = (short)bf16_rne(a1.x); t[5] = (short)bf16_rne(a1.y);
            t[6] = (short)bf16_rne(a1.z); t[7] = (short)bf16_rne(a1.w);
            ah[ks] = t;
        }

        f32x4 acc[16];
        #pragma unroll
        for (int t = 0; t < 16; ++t) acc[t] = (f32x4){0.f, 0.f, 0.f, 0.f};
        #pragma unroll
        for (int t = 0; t < 16; ++t) {
            #pragma unroll
            for (int ks = 0; ks < 4; ++ks) {
                bf16x8 b = *(const bf16x8*)&sm.s.cbf[t*16 + fr][ks*32 + g*8];
                acc[t] = __builtin_amdgcn_mfma_f32_16x16x32_bf16(ah[ks], b, acc[t], 0, 0, 0);
            }
        }

        float csqv[16];
        #pragma unroll
        for (int t = 0; t < 16; ++t) csqv[t] = sm.s.csqL[t*16 + fr];

        float m1r[4];
        #pragma unroll
        for (int r = 0; r < 4; ++r) {
            float m = 1e30f;
            #pragma unroll
            for (int t = 0; t < 16; ++t) { float s = csqv[t] - 2.f*acc[t][r]; m = fminf(m, s); }
            #pragma unroll
            for (int off = 1; off < 16; off <<= 1) m = fminf(m, __shfl_xor(m, off));
            m1r[r] = m;
        }
        #pragma unroll
        for (int t = 0; t < 16; ++t)
            #pragma unroll
            for (int r = 0; r < 4; ++r) {
                float s = csqv[t] - 2.f*acc[t][r];
                if (s <= m1r[r] + WMARG) {
                    int row = w*16 + g*4 + r;
                    unsigned int slot = atomicAdd(&sm.s.pcnt[row], 1u);
                    if (slot < CAPP) sm.s.plist[row][slot] = (unsigned char)(t*16 + fr);
                }
            }
        __syncthreads();

        {   // exact np rescue: 4 threads per point (centers via L3 atomics)
            const int pt = tid & 127, q = tid >> 7;
            unsigned int ccnt = sm.s.pcnt[pt];
            int cnt = (ccnt < (unsigned)CAPP) ? (int)ccnt : CAPP;
            unsigned int bkey = 0xFFFFFFFFu; int bn = 255;
            const float xs_ = sm.s.xsqL[pt];
            const float* xp = &sm.s.xf[pt][0];
            for (int i = q; i < cnt; i += 4) {
                int kk = sm.s.plist[pt][i];
                const float* cp = &centers[(size_t)kk*DIM];
                float dot = 0.f;
                for (int d0 = 0; d0 < DIM; d0 += 16) {
                    float4 c0 = ald_f4(cp + d0);
                    float4 c1 = ald_f4(cp + d0 + 4);
                    float4 c2 = ald_f4(cp + d0 + 8);
                    float4 c3 = ald_f4(cp + d0 + 12);
                    float4 xa = *(const float4*)(xp + d0);
                    float4 xb = *(const float4*)(xp + d0 + 4);
                    float4 xc = *(const float4*)(xp + d0 + 8);
                    float4 xd = *(const float4*)(xp + d0 + 12);
                    dot = fmaf(xa.x, c0.x, dot); dot = fmaf(xa.y, c0.y, dot);
                    dot = fmaf(xa.z, c0.z, dot); dot = fmaf(xa.w, c0.w, dot);
                    dot = fmaf(xb.x, c1.x, dot); dot = fmaf(xb.y, c1.y, dot);
                    dot = fmaf(xb.z, c1.z, dot); dot = fmaf(xb.w, c1.w, dot);
                    dot = fmaf(xc.x, c2.x, dot); dot = fmaf(xc.y, c2.y, dot);
                    dot = fmaf(xc.z, c2.z, dot); dot = fmaf(xc.w, c2.w, dot);
                    dot = fmaf(xd.x, c3.x, dot); dot = fmaf(xd.y, c3.y, dot);
                    dot = fmaf(xd.z, c3.z, dot); dot = fmaf(xd.w, c3.w, dot);
                }
                float d2;
                {
                    #pragma clang fp contract(off)
                    float m = 2.f*dot;
                    float t = xs_ + sm.s.csqL[kk];
                    d2 = t - m;
                }
                unsigned int b = __float_as_uint(d2);
                unsigned int key = (b & 0x80000000u) ? ~b : (b | 0x80000000u);
                if (key < bkey || (key == bkey && kk < bn)) { bkey = key; bn = kk; }
            }
            sm.s.smink[q][pt] = bkey;
            sm.s.sminn[q][pt] = (unsigned char)bn;
        }
        __syncthreads();
        if (tid < 128) {
            unsigned int Bk = sm.s.smink[0][tid]; int Bn = sm.s.sminn[0][tid];
            #pragma unroll
            for (int q = 1; q < 4; ++q) {
                unsigned int u = sm.s.smink[q][tid]; int n = sm.s.sminn[q][tid];
                if (u < Bk || (u == Bk && n < Bn)) { Bk = u; Bn = n; }
            }
            ast_u8(&assignv[bid*128 + tid], (unsigned char)Bn);  // first-min == np.argmin
        }
        gbar(arrive, tgt += NB);

        // ================= seg phase =================
        {
            const int k = bid;
            int cnt = 0;
            u64 v[8];
            #pragma unroll
            for (int j = 0; j < 8; ++j) v[j] = ald64(assignv + (size_t)(tid*8 + j)*8);
            #pragma unroll
            for (int j = 0; j < 8; ++j)
                #pragma unroll
                for (int e = 0; e < 8; ++e)
                    cnt += (int)(((v[j] >> (8*e)) & 0xFFu) == (unsigned)k);

            int incl = cnt;
            #pragma unroll
            for (int off = 1; off < 64; off <<= 1) {
                int o = __shfl_up(incl, off);
                if (lane >= off) incl += o;
            }
            if (lane == 63) sm.g.tsum[w] = incl;
            __syncthreads();
            int woff = 0, L = 0;
            #pragma unroll
            for (int ww = 0; ww < 8; ++ww) {
                woff += (ww < w) ? sm.g.tsum[ww] : 0;
                L += sm.g.tsum[ww];
            }
            int wpos = incl - cnt + woff;
            #pragma unroll
            for (int j = 0; j < 8; ++j) {
                u64 vv = v[j];
                int n0 = tid*64 + j*8;
                #pragma unroll
                for (int e = 0; e < 8; ++e)
                    if (((vv >> (8*e)) & 0xFFu) == (unsigned)k) sm.g.nlist[wpos++] = n0 + e;
            }
            __syncthreads();

            if (tid < 128) {
                const int d = tid;
                float nv;
                if (L > 0) {
                    #pragma clang fp contract(off)
                    float vA[FT], vB[FT];
                    float s = 0.f;
                    const int nt = (L + FT - 1) / FT;
                    LOADL(vA, 0);
                    for (int t = 0; t < nt; t += 2) {
                        LOADL(vB, t+1);
                        FOLDL(vA, t);
                        LOADL(vA, t+2);
                        FOLDL(vB, t+1);
                    }
                    float c = (float)L;
                    nv = s / fmaxf(c, 1.f);                  // IEEE div == np
                    ast_f(&centers[(size_t)k*DIM + d], nv);  // write only if L>0
                } else {
                    nv = ald_f(&centers[(size_t)k*DIM + d]);
                }
                ast_u16(&cbfg[(size_t)k*DIM + d], bf16_rne(nv));
                sm.g.rowv[d] = nv;
            }
            __syncthreads();
            if (tid == 0) ast_f(&csqg[bid], np_sumsq128(sm.g.rowv, 1));
        }
        gbar(arrive, tgt += NB);
    }

    // ================= makeM phase =================
    if (tid < 128) {
        const int k = bid, d = tid;
        float s = 0.f;
        #pragma unroll 8
        for (int i = 0; i < K; ++i) s = fmaf(W[k*K + i], ald_f(&centers[(size_t)i*DIM + d]), s);
        s *= (1.f/128.f);
        unsigned short h = bf16_rne(s);
        float lo = s - bf16_to_f(h);
        unsigned short l2 = bf16_rne(lo);
        Mh[k*DIM + d] = h;
        Ml[k*DIM + d] = l2;
        out_centers[k*DIM + d] = ald_f(&centers[(size_t)k*DIM + d]);
    }
}

// ---------------- out = X @ M^T via bf16-split MFMA (proven r8) ----------------
__global__ __launch_bounds__(256, 2) void k_out_mfma(
    const float* __restrict__ x, const unsigned short* __restrict__ Mh,
    const unsigned short* __restrict__ Ml, float* __restrict__ outp)
{
    __shared__ unsigned short AhL[32][DIM+8];
    __shared__ unsigned short AlL[32][DIM+8];

    const int tid = threadIdx.x, lane = tid & 63, w = tid >> 6;

    bf16x8 bh[4][4], bl[4][4];
    #pragma unroll
    for (int tt = 0; tt < 4; ++tt)
        #pragma unroll
        for (int s = 0; s < 4; ++s) {
            int col = (w*4 + tt)*16 + (lane & 15);
            int off = col*DIM + 32*s + (lane >> 4)*8;
            bh[tt][s] = *(const bf16x8*)&Mh[off];
            bl[tt][s] = *(const bf16x8*)&Ml[off];
        }

    for (int strip = blockIdx.x; strip < NALL/32; strip += gridDim.x) {
        const int sbase = strip * 32;
        __syncthreads();
        const float4* x4 = (const float4*)x;
        #pragma unroll
        for (int i = 0; i < 4; ++i) {
            int idx = i*256 + tid;
            int row = idx >> 5, c4 = idx & 31;
            float4 v = x4[(size_t)(sbase + row)*32 + c4];
            ushort4 hh, ll;
            float f; unsigned short h;
            f = v.x; h = bf16_rne(f); hh.x = h; ll.x = bf16_rne(f - bf16_to_f(h));
            f = v.y; h = bf16_rne(f); hh.y = h; ll.y = bf16_rne(f - bf16_to_f(h));
            f = v.z; h = bf16_rne(f); hh.z = h; ll.z = bf16_rne(f - bf16_to_f(h));
            f = v.w; h = bf16_rne(f); hh.w = h; ll.w = bf16_rne(f - bf16_to_f(h));
            *(ushort4*)&AhL[row][c4*4] = hh;
            *(ushort4*)&AlL[row][c4*4] = ll;
        }
        __syncthreads();

        f32x4 acc[2][4];
        #pragma unroll
        for (int rt = 0; rt < 2; ++rt)
            #pragma unroll
            for (int tt = 0; tt < 4; ++tt)
                acc[rt][tt] = (f32x4){0.f, 0.f, 0.f, 0.f};

        #pragma unroll
        for (int s = 0; s < 4; ++s) {
            bf16x8 ah[2], al[2];
            #pragma unroll
            for (int rt = 0; rt < 2; ++rt) {
                int r = (lane & 15) + 16*rt;
                int kc = 32*s + (lane >> 4)*8;
                ah[rt] = *(const bf16x8*)&AhL[r][kc];
                al[rt] = *(const bf16x8*)&AlL[r][kc];
            }
            #pragma unroll
            for (int rt = 0; rt < 2; ++rt)
                #pragma unroll
                for (int tt = 0; tt < 4; ++tt) {
                    acc[rt][tt] = __builtin_amdgcn_mfma_f32_16x16x32_bf16(ah[rt], bh[tt][s], acc[rt][tt], 0, 0, 0);
                    acc[rt][tt] = __builtin_amdgcn_mfma_f32_16x16x32_bf16(ah[rt], bl[tt][s], acc[rt][tt], 0, 0, 0);
                    acc[rt][tt] = __builtin_amdgcn_mfma_f32_16x16x32_bf16(al[rt], bh[tt][s], acc[rt][tt], 0, 0, 0);
                }
        }

        #pragma unroll
        for (int rt = 0; rt < 2; ++rt)
            #pragma unroll
            for (int tt = 0; tt < 4; ++tt)
                #pragma unroll
                for (int reg = 0; reg < 4; ++reg) {
                    int row = sbase + rt*16 + (lane >> 4)*4 + reg;
                    int col = w*64 + tt*16 + (lane & 15);
                    outp[(size_t)row*K + col] = acc[rt][tt][reg];
                }
    }
}

extern "C" void kernel_launch(void* const* d_in, const int* in_sizes, int n_in,
                              void* d_out, int out_size, void* d_ws, size_t ws_size,
                              hipStream_t stream)
{
    const float* x = (const float*)d_in[0];   // [8][32768][128]
    const float* W = (const float*)d_in[1];   // [256][256]
    float* outp        = (float*)d_out;                       // [262144][256]
    float* out_centers = outp + (size_t)NALL * K;             // [256][128]

    // workspace layout (4B units)
    float* ws       = (float*)d_ws;
    float* centers  = ws;                                 // 32768 f32
    unsigned char* assignv = (unsigned char*)(ws + 32768);// 32768 uchar (8 KB used of 128 KB slot)
    unsigned short* Mh = (unsigned short*)(ws + 65536);   // 32768 ushort
    unsigned short* Ml = (unsigned short*)(ws + 81920);   // 32768 ushort
    unsigned short* cbfg = (unsigned short*)(ws + 98304); // 32768 ushort
    float* csqg     = ws + 114688;                        // 256
    unsigned int* arrive = (unsigned int*)(ws + 114944);  // 1
    (void)ws_size;

    k_init<<<K, DIM, 0, stream>>>(x, centers, cbfg, csqg, arrive);
    k_all<<<NB, 512, 0, stream>>>(x, W, centers, assignv, cbfg, csqg,
                                  Mh, Ml, out_centers, arrive);
    k_out_mfma<<<2048, 256, 0, stream>>>(x, Mh, Ml, outp);
}

// Round 16
// 871.697 us; speedup vs baseline: 1.5237x; 1.5237x over previous
//
#include <hip/hip_runtime.h>

#define DIM    128
#define K      256
#define NPTS   32768
#define NALL   (8*32768)
#define ITERS  10
#define FT     64
#define WMARG  6.0f          // screen window: >3x the rigorous |s_bf - s_np| bound
#define CAPP   48            // per-point candidate cap

typedef short bf16x8 __attribute__((ext_vector_type(8)));
typedef float f32x4  __attribute__((ext_vector_type(4)));

__device__ __forceinline__ unsigned short bf16_rne(float f) {
    unsigned int u = __float_as_uint(f);
    unsigned int r = u + 0x7fffu + ((u >> 16) & 1u);
    return (unsigned short)(r >> 16);
}
__device__ __forceinline__ float bf16_to_f(unsigned short h) {
    return __uint_as_float(((unsigned int)h) << 16);
}

// numpy pairwise sum of squares, n=128, SSE2 path (scalar loads)
__device__ __forceinline__ float np_sumsq128(const float* p, int stride) {
    #pragma clang fp contract(off)
    float c[8];
    #pragma unroll
    for (int j = 0; j < 8; ++j) { float x = p[j*stride]; c[j] = x*x; }
    #pragma unroll
    for (int t = 1; t < 16; ++t)
        #pragma unroll
        for (int j = 0; j < 8; ++j) { float x = p[(8*t+j)*stride]; c[j] = c[j] + x*x; }
    float v0 = c[0] + c[4];
    float v1 = c[1] + c[5];
    float v2 = c[2] + c[6];
    float v3 = c[3] + c[7];
    return (v0 + v2) + (v1 + v3);
}

// same tree, float4 loads (identical arithmetic order -> identical bits)
__device__ __forceinline__ float np_sumsq128_f4(const float* p) {
    #pragma clang fp contract(off)
    float c[8];
    {
        float4 a = *(const float4*)p, b = *(const float4*)(p + 4);
        c[0]=a.x*a.x; c[1]=a.y*a.y; c[2]=a.z*a.z; c[3]=a.w*a.w;
        c[4]=b.x*b.x; c[5]=b.y*b.y; c[6]=b.z*b.z; c[7]=b.w*b.w;
    }
    #pragma unroll
    for (int t = 1; t < 16; ++t) {
        float4 a = *(const float4*)(p + 8*t), b = *(const float4*)(p + 8*t + 4);
        c[0]=c[0]+a.x*a.x; c[1]=c[1]+a.y*a.y; c[2]=c[2]+a.z*a.z; c[3]=c[3]+a.w*a.w;
        c[4]=c[4]+b.x*b.x; c[5]=c[5]+b.y*b.y; c[6]=c[6]+b.z*b.z; c[7]=c[7]+b.w*b.w;
    }
    float v0 = c[0] + c[4];
    float v1 = c[1] + c[5];
    float v2 = c[2] + c[6];
    float v3 = c[3] + c[7];
    return (v0 + v2) + (v1 + v3);
}

// ---------------- init: centers = X0[:256], plus cbfg/csq ----------------
__global__ __launch_bounds__(DIM) void k_init(
    const float* __restrict__ x0, float* __restrict__ centers,
    unsigned short* __restrict__ cbfg, float* __restrict__ csqg)
{
    __shared__ float rowv[DIM];
    const int k = blockIdx.x, d = threadIdx.x;
    float v = x0[(size_t)k*DIM + d];
    centers[(size_t)k*DIM + d] = v;
    cbfg[(size_t)k*DIM + d] = bf16_rne(v);
    rowv[d] = v;
    __syncthreads();
    if (d == 0) csqg[k] = np_sumsq128(rowv, 1);
}

// ---------------- assignment: bf16-MFMA screen + exact np rescue ----------------
__global__ __launch_bounds__(512, 1) void k_screen(
    const float* __restrict__ x0, const float* __restrict__ centers,
    const unsigned short* __restrict__ cbfg, const float* __restrict__ csqg,
    int* __restrict__ assignv)
{
    __shared__ float          xf[128][132];
    __shared__ unsigned short cbf[256][136];
    __shared__ float          csqL[K];
    __shared__ float          xsqL[128];
    __shared__ unsigned int   pcnt[128];
    __shared__ unsigned char  plist[128][CAPP];
    __shared__ unsigned int   smink[4][128];
    __shared__ unsigned char  sminn[4][128];

    const int tid = threadIdx.x, lane = tid & 63, w = tid >> 6;
    const int g = lane >> 4, fr = lane & 15;

    if (tid < 128) pcnt[tid] = 0u;

    {
        const uint4* c8p = (const uint4*)cbfg;
        #pragma unroll
        for (int i = 0; i < 8; ++i) {
            int idx = i*512 + tid;
            int row = idx >> 4, c8 = idx & 15;
            *(uint4*)&cbf[row][c8*8] = c8p[idx];
        }
    }
    {
        const float4* x4 = (const float4*)x0 + (size_t)blockIdx.x*128*32;
        #pragma unroll
        for (int i = 0; i < 8; ++i) {
            int idx = i*512 + tid;
            int row = idx >> 5, c4 = idx & 31;
            *(float4*)&xf[row][c4*4] = x4[idx];
        }
    }
    __syncthreads();

    if (tid < 256) csqL[tid] = csqg[tid];
    if (tid < 128) xsqL[tid] = np_sumsq128_f4(&xf[tid][0]);
    __syncthreads();

    // ---- screen GEMM: wave w owns rows 16w..16w+15, all 256 k ----
    bf16x8 ah[4];
    #pragma unroll
    for (int ks = 0; ks < 4; ++ks) {
        const float* xp = &xf[w*16 + fr][ks*32 + g*8];
        float4 a0 = *(const float4*)xp;
        float4 a1 = *(const float4*)(xp + 4);
        bf16x8 t;
        t[0] = (short)bf16_rne(a0.x); t[1] = (short)bf16_rne(a0.y);
        t[2] = (short)bf16_rne(a0.z); t[3] = (short)bf16_rne(a0.w);
        t[4] = (short)bf16_rne(a1.x); t[5] = (short)bf16_rne(a1.y);
        t[6] = (short)bf16_rne(a1.z); t[7] = (short)bf16_rne(a1.w);
        ah[ks] = t;
    }

    f32x4 acc[16];
    #pragma unroll
    for (int t = 0; t < 16; ++t) acc[t] = (f32x4){0.f, 0.f, 0.f, 0.f};
    #pragma unroll
    for (int t = 0; t < 16; ++t) {
        #pragma unroll
        for (int ks = 0; ks < 4; ++ks) {
            bf16x8 b = *(const bf16x8*)&cbf[t*16 + fr][ks*32 + g*8];
            acc[t] = __builtin_amdgcn_mfma_f32_16x16x32_bf16(ah[ks], b, acc[t], 0, 0, 0);
        }
    }

    float csqv[16];
    #pragma unroll
    for (int t = 0; t < 16; ++t) csqv[t] = csqL[t*16 + fr];

    float m1r[4];
    #pragma unroll
    for (int r = 0; r < 4; ++r) {
        float m = 1e30f;
        #pragma unroll
        for (int t = 0; t < 16; ++t) { float s = csqv[t] - 2.f*acc[t][r]; m = fminf(m, s); }
        #pragma unroll
        for (int off = 1; off < 16; off <<= 1) m = fminf(m, __shfl_xor(m, off));
        m1r[r] = m;
    }
    #pragma unroll
    for (int t = 0; t < 16; ++t)
        #pragma unroll
        for (int r = 0; r < 4; ++r) {
            float s = csqv[t] - 2.f*acc[t][r];
            if (s <= m1r[r] + WMARG) {
                int row = w*16 + g*4 + r;
                unsigned int slot = atomicAdd(&pcnt[row], 1u);
                if (slot < CAPP) plist[row][slot] = (unsigned char)(t*16 + fr);
            }
        }
    __syncthreads();

    // ---- exact np rescue: 4 threads per point, 2 interleaved chains each ----
    {
        const int pt = tid & 127, q = tid >> 7;
        unsigned int ccnt = pcnt[pt];
        int cnt = (ccnt < (unsigned)CAPP) ? (int)ccnt : CAPP;
        unsigned int bkey = 0xFFFFFFFFu; int bn = 255;
        const float xs_ = xsqL[pt];
        const float* xp = &xf[pt][0];
        for (int i = q; i < cnt; i += 8) {
            int kk0 = plist[pt][i];
            int i1 = i + 4;
            bool has2 = (i1 < cnt);
            int kk1 = has2 ? plist[pt][i1] : kk0;
            const float* cp0 = &centers[(size_t)kk0*DIM];
            const float* cp1 = &centers[(size_t)kk1*DIM];
            float dot0 = 0.f, dot1 = 0.f;
            #pragma unroll
            for (int d0 = 0; d0 < DIM; d0 += 8) {
                float4 a0 = *(const float4*)(cp0 + d0);
                float4 a1 = *(const float4*)(cp0 + d0 + 4);
                float4 b0 = *(const float4*)(cp1 + d0);
                float4 b1 = *(const float4*)(cp1 + d0 + 4);
                float4 xa = *(const float4*)(xp + d0);
                float4 xb = *(const float4*)(xp + d0 + 4);
                dot0 = fmaf(xa.x, a0.x, dot0); dot1 = fmaf(xa.x, b0.x, dot1);
                dot0 = fmaf(xa.y, a0.y, dot0); dot1 = fmaf(xa.y, b0.y, dot1);
                dot0 = fmaf(xa.z, a0.z, dot0); dot1 = fmaf(xa.z, b0.z, dot1);
                dot0 = fmaf(xa.w, a0.w, dot0); dot1 = fmaf(xa.w, b0.w, dot1);
                dot0 = fmaf(xb.x, a1.x, dot0); dot1 = fmaf(xb.x, b1.x, dot1);
                dot0 = fmaf(xb.y, a1.y, dot0); dot1 = fmaf(xb.y, b1.y, dot1);
                dot0 = fmaf(xb.z, a1.z, dot0); dot1 = fmaf(xb.z, b1.z, dot1);
                dot0 = fmaf(xb.w, a1.w, dot0); dot1 = fmaf(xb.w, b1.w, dot1);
            }
            {
                #pragma clang fp contract(off)
                float m0 = 2.f*dot0;
                float t0 = xs_ + csqL[kk0];
                float d2 = t0 - m0;
                unsigned int b = __float_as_uint(d2);
                unsigned int key = (b & 0x80000000u) ? ~b : (b | 0x80000000u);
                if (key < bkey || (key == bkey && kk0 < bn)) { bkey = key; bn = kk0; }
                if (has2) {
                    float m1 = 2.f*dot1;
                    float t1 = xs_ + csqL[kk1];
                    float e2 = t1 - m1;
                    unsigned int b2 = __float_as_uint(e2);
                    unsigned int key2 = (b2 & 0x80000000u) ? ~b2 : (b2 | 0x80000000u);
                    if (key2 < bkey || (key2 == bkey && kk1 < bn)) { bkey = key2; bn = kk1; }
                }
            }
        }
        smink[q][pt] = bkey;
        sminn[q][pt] = (unsigned char)bn;
    }
    __syncthreads();
    if (tid < 128) {
        unsigned int Bk = smink[0][tid]; int Bn = sminn[0][tid];
        #pragma unroll
        for (int q = 1; q < 4; ++q) {
            unsigned int u = smink[q][tid]; int n = sminn[q][tid];
            if (u < Bk || (u == Bk && n < Bn)) { Bk = u; Bn = n; }
        }
        assignv[blockIdx.x*128 + tid] = Bn;   // first-min tie rule == np.argmin
    }
}

// ---------------- fused segment-sum + update + cbf/csq emit ----------------
// 512 threads: waves 0-1 fold (exact np.add.at ascending-n left-fold),
// waves 2-7 best-effort L2-prefetch of the cluster's x0 rows.
// NOTE guard must be idx_ < L (entries >= L are uninitialized LDS; r15 crash).
#define LOADL(vv, t0) do {                                                  \
    int base_ = (t0)*FT;                                                    \
    int nn_[FT];                                                            \
    _Pragma("unroll")                                                       \
    for (int j = 0; j < FT; ++j) {                                          \
        int idx_ = base_ + j;                                               \
        nn_[j] = nlist[idx_ < L ? idx_ : 0];                                \
    }                                                                       \
    _Pragma("unroll")                                                       \
    for (int j = 0; j < FT; ++j) vv[j] = x0[(size_t)nn_[j]*DIM + d];        \
} while (0)

#define FOLDL(vv, t0) do {                                                  \
    int rem_ = L - (t0)*FT;                                                 \
    if (rem_ >= FT) {                                                       \
        _Pragma("unroll")                                                   \
        for (int j = 0; j < FT; ++j) s = s + vv[j];                         \
    } else if (rem_ > 0) {                                                  \
        _Pragma("unroll")                                                   \
        for (int j = 0; j < FT; ++j) { float t_ = s + vv[j]; s = (j < rem_) ? t_ : s; } \
    }                                                                       \
} while (0)

__global__ __launch_bounds__(512, 1) void k_seg(
    const float* __restrict__ x0, const int* __restrict__ assignv,
    float* __restrict__ centers, unsigned short* __restrict__ cbfg,
    float* __restrict__ csqg)
{
    __shared__ int nlist[NPTS];        // 128 KB
    __shared__ int tsum[8];
    __shared__ float rowv[DIM];
    const int k   = blockIdx.x;
    const int tid = threadIdx.x, lane = tid & 63, w = tid >> 6;

    // scan + compact (512 threads, r12-proven): thread range = 64 pts = 16 int4
    const int4* a4 = (const int4*)assignv;
    int cnt = 0;
    {
        for (int b = 0; b < 16; b += 8) {
            int4 v[8];
            #pragma unroll
            for (int j = 0; j < 8; ++j) v[j] = a4[tid*16 + b + j];
            #pragma unroll
            for (int j = 0; j < 8; ++j)
                cnt += (v[j].x == k) + (v[j].y == k) + (v[j].z == k) + (v[j].w == k);
        }
    }
    int incl = cnt;
    #pragma unroll
    for (int off = 1; off < 64; off <<= 1) {
        int o = __shfl_up(incl, off);
        if (lane >= off) incl += o;
    }
    if (lane == 63) tsum[w] = incl;
    __syncthreads();
    int woff = 0, L = 0;
    #pragma unroll
    for (int ww = 0; ww < 8; ++ww) {
        woff += (ww < w) ? tsum[ww] : 0;
        L += tsum[ww];
    }
    int wpos = incl - cnt + woff;
    for (int b = 0; b < 16; b += 8) {
        int4 v[8];
        #pragma unroll
        for (int j = 0; j < 8; ++j) v[j] = a4[tid*16 + b + j];
        #pragma unroll
        for (int j = 0; j < 8; ++j) {
            int n0 = tid*64 + (b+j)*4;
            if (v[j].x == k) nlist[wpos++] = n0;
            if (v[j].y == k) nlist[wpos++] = n0+1;
            if (v[j].z == k) nlist[wpos++] = n0+2;
            if (v[j].w == k) nlist[wpos++] = n0+3;
        }
    }
    __syncthreads();

    if (tid < 128) {
        const int d = tid;
        float nv;
        if (L > 0) {
            #pragma clang fp contract(off)
            float vA[FT], vB[FT];
            float s = 0.f;
            const int nt = (L + FT - 1) / FT;
            LOADL(vA, 0);
            for (int t = 0; t < nt; t += 2) {
                LOADL(vB, t+1);
                FOLDL(vA, t);
                LOADL(vA, t+2);
                FOLDL(vB, t+1);
            }
            float c = (float)L;
            nv = s / fmaxf(c, 1.f);                  // IEEE div == np
            centers[(size_t)k*DIM + d] = nv;         // write only if L>0 (np.where)
        } else {
            nv = centers[(size_t)k*DIM + d];
        }
        cbfg[(size_t)k*DIM + d] = bf16_rne(nv);
        rowv[d] = nv;
    } else if (L > 256) {
        // waves 2-7: best-effort L2 prefetch (read-only, guarded to [0, L))
        const int i = tid - 128;                 // 0..383
        const int lineoff = (i & 3) * 32;        // 4 x 128B lines per 512B row
        for (int r = (i >> 2); r < L; r += 96*32) {
            float vkeep[32];
            #pragma unroll
            for (int b = 0; b < 32; ++b) {
                int rr = r + b*96;
                int nn = nlist[rr < L ? rr : 0];
                vkeep[b] = x0[(size_t)nn*DIM + lineoff];
            }
            #pragma unroll
            for (int b = 0; b < 32; ++b) asm volatile("" :: "v"(vkeep[b]));
        }
    }
    __syncthreads();
    if (tid == 0) csqg[k] = np_sumsq128(rowv, 1);
}

// ---------------- M = W @ centers / 128 (fp32), split to bf16 hi/lo ----------------
__global__ void k_makeM(const float* __restrict__ W, const float* __restrict__ centers,
                        unsigned short* __restrict__ Mh, unsigned short* __restrict__ Ml,
                        float* __restrict__ out_centers)
{
    int k = blockIdx.x, d = threadIdx.x;
    float s = 0.f;
    #pragma unroll 8
    for (int i = 0; i < K; ++i) s = fmaf(W[k*K + i], centers[i*DIM + d], s);
    s *= (1.f/128.f);
    unsigned short h = bf16_rne(s);
    float lo = s - bf16_to_f(h);
    unsigned short l2 = bf16_rne(lo);
    Mh[k*DIM + d] = h;
    Ml[k*DIM + d] = l2;
    out_centers[k*DIM + d] = centers[k*DIM + d];
}

// ---------------- out = X @ M^T via bf16-split MFMA (proven r8) ----------------
__global__ __launch_bounds__(256, 2) void k_out_mfma(
    const float* __restrict__ x, const unsigned short* __restrict__ Mh,
    const unsigned short* __restrict__ Ml, float* __restrict__ outp)
{
    __shared__ unsigned short AhL[32][DIM+8];
    __shared__ unsigned short AlL[32][DIM+8];

    const int tid = threadIdx.x, lane = tid & 63, w = tid >> 6;

    bf16x8 bh[4][4], bl[4][4];
    #pragma unroll
    for (int tt = 0; tt < 4; ++tt)
        #pragma unroll
        for (int s = 0; s < 4; ++s) {
            int col = (w*4 + tt)*16 + (lane & 15);
            int off = col*DIM + 32*s + (lane >> 4)*8;
            bh[tt][s] = *(const bf16x8*)&Mh[off];
            bl[tt][s] = *(const bf16x8*)&Ml[off];
        }

    for (int strip = blockIdx.x; strip < NALL/32; strip += gridDim.x) {
        const int sbase = strip * 32;
        __syncthreads();
        const float4* x4 = (const float4*)x;
        #pragma unroll
        for (int i = 0; i < 4; ++i) {
            int idx = i*256 + tid;
            int row = idx >> 5, c4 = idx & 31;
            float4 v = x4[(size_t)(sbase + row)*32 + c4];
            ushort4 hh, ll;
            float f; unsigned short h;
            f = v.x; h = bf16_rne(f); hh.x = h; ll.x = bf16_rne(f - bf16_to_f(h));
            f = v.y; h = bf16_rne(f); hh.y = h; ll.y = bf16_rne(f - bf16_to_f(h));
            f = v.z; h = bf16_rne(f); hh.z = h; ll.z = bf16_rne(f - bf16_to_f(h));
            f = v.w; h = bf16_rne(f); hh.w = h; ll.w = bf16_rne(f - bf16_to_f(h));
            *(ushort4*)&AhL[row][c4*4] = hh;
            *(ushort4*)&AlL[row][c4*4] = ll;
        }
        __syncthreads();

        f32x4 acc[2][4];
        #pragma unroll
        for (int rt = 0; rt < 2; ++rt)
            #pragma unroll
            for (int tt = 0; tt < 4; ++tt)
                acc[rt][tt] = (f32x4){0.f, 0.f, 0.f, 0.f};

        #pragma unroll
        for (int s = 0; s < 4; ++s) {
            bf16x8 ah[2], al[2];
            #pragma unroll
            for (int rt = 0; rt < 2; ++rt) {
                int r = (lane & 15) + 16*rt;
                int kc = 32*s + (lane >> 4)*8;
                ah[rt] = *(const bf16x8*)&AhL[r][kc];
                al[rt] = *(const bf16x8*)&AlL[r][kc];
            }
            #pragma unroll
            for (int rt = 0; rt < 2; ++rt)
                #pragma unroll
                for (int tt = 0; tt < 4; ++tt) {
                    acc[rt][tt] = __builtin_amdgcn_mfma_f32_16x16x32_bf16(ah[rt], bh[tt][s], acc[rt][tt], 0, 0, 0);
                    acc[rt][tt] = __builtin_amdgcn_mfma_f32_16x16x32_bf16(ah[rt], bl[tt][s], acc[rt][tt], 0, 0, 0);
                    acc[rt][tt] = __builtin_amdgcn_mfma_f32_16x16x32_bf16(al[rt], bh[tt][s], acc[rt][tt], 0, 0, 0);
                }
        }

        #pragma unroll
        for (int rt = 0; rt < 2; ++rt)
            #pragma unroll
            for (int tt = 0; tt < 4; ++tt)
                #pragma unroll
                for (int reg = 0; reg < 4; ++reg) {
                    int row = sbase + rt*16 + (lane >> 4)*4 + reg;
                    int col = w*64 + tt*16 + (lane & 15);
                    outp[(size_t)row*K + col] = acc[rt][tt][reg];
                }
    }
}

extern "C" void kernel_launch(void* const* d_in, const int* in_sizes, int n_in,
                              void* d_out, int out_size, void* d_ws, size_t ws_size,
                              hipStream_t stream)
{
    const float* x = (const float*)d_in[0];   // [8][32768][128]
    const float* W = (const float*)d_in[1];   // [256][256]
    float* outp        = (float*)d_out;                       // [262144][256]
    float* out_centers = outp + (size_t)NALL * K;             // [256][128]

    // workspace layout (4B units)
    float* ws       = (float*)d_ws;
    float* centers  = ws;                                 // 32768
    int*   assignv  = (int*)(ws + 32768);                 // 32768
    unsigned short* Mh = (unsigned short*)(ws + 65536);   // 32768 ushort
    unsigned short* Ml = (unsigned short*)(ws + 81920);   // 32768 ushort
    unsigned short* cbfg = (unsigned short*)(ws + 98304); // 32768 ushort
    float* csqg     = ws + 114688;                        // 256
    (void)ws_size;

    k_init<<<K, DIM, 0, stream>>>(x, centers, cbfg, csqg);
    for (int it = 0; it < ITERS; ++it) {
        k_screen<<<NPTS/128, 512, 0, stream>>>(x, centers, cbfg, csqg, assignv);
        k_seg   <<<K, 512, 0, stream>>>(x, assignv, centers, cbfg, csqg);
    }
    k_makeM<<<K, DIM, 0, stream>>>(W, centers, Mh, Ml, out_centers);
    k_out_mfma<<<2048, 256, 0, stream>>>(x, Mh, Ml, outp);
}

// Round 17
// 756.851 us; speedup vs baseline: 1.7549x; 1.1517x over previous
//
#include <hip/hip_runtime.h>

#define DIM    128
#define K      256
#define NPTS   32768
#define NALL   (8*32768)
#define ITERS  10
#define FT     64
#define WMARG  6.0f          // screen window: >3x the rigorous |s_bf - s_np| bound
#define CAPP   48            // per-point candidate cap

typedef short bf16x8 __attribute__((ext_vector_type(8)));
typedef float f32x4  __attribute__((ext_vector_type(4)));

__device__ __forceinline__ unsigned short bf16_rne(float f) {
    unsigned int u = __float_as_uint(f);
    unsigned int r = u + 0x7fffu + ((u >> 16) & 1u);
    return (unsigned short)(r >> 16);
}
__device__ __forceinline__ float bf16_to_f(unsigned short h) {
    return __uint_as_float(((unsigned int)h) << 16);
}

// numpy pairwise sum of squares, n=128, SSE2 path (scalar loads)
__device__ __forceinline__ float np_sumsq128(const float* p, int stride) {
    #pragma clang fp contract(off)
    float c[8];
    #pragma unroll
    for (int j = 0; j < 8; ++j) { float x = p[j*stride]; c[j] = x*x; }
    #pragma unroll
    for (int t = 1; t < 16; ++t)
        #pragma unroll
        for (int j = 0; j < 8; ++j) { float x = p[(8*t+j)*stride]; c[j] = c[j] + x*x; }
    float v0 = c[0] + c[4];
    float v1 = c[1] + c[5];
    float v2 = c[2] + c[6];
    float v3 = c[3] + c[7];
    return (v0 + v2) + (v1 + v3);
}

// same tree, float4 loads (identical arithmetic order -> identical bits)
__device__ __forceinline__ float np_sumsq128_f4(const float* p) {
    #pragma clang fp contract(off)
    float c[8];
    {
        float4 a = *(const float4*)p, b = *(const float4*)(p + 4);
        c[0]=a.x*a.x; c[1]=a.y*a.y; c[2]=a.z*a.z; c[3]=a.w*a.w;
        c[4]=b.x*b.x; c[5]=b.y*b.y; c[6]=b.z*b.z; c[7]=b.w*b.w;
    }
    #pragma unroll
    for (int t = 1; t < 16; ++t) {
        float4 a = *(const float4*)(p + 8*t), b = *(const float4*)(p + 8*t + 4);
        c[0]=c[0]+a.x*a.x; c[1]=c[1]+a.y*a.y; c[2]=c[2]+a.z*a.z; c[3]=c[3]+a.w*a.w;
        c[4]=c[4]+b.x*b.x; c[5]=c[5]+b.y*b.y; c[6]=c[6]+b.z*b.z; c[7]=c[7]+b.w*b.w;
    }
    float v0 = c[0] + c[4];
    float v1 = c[1] + c[5];
    float v2 = c[2] + c[6];
    float v3 = c[3] + c[7];
    return (v0 + v2) + (v1 + v3);
}

// ---------------- init: centers = X0[:256], plus cbfg/csq ----------------
__global__ __launch_bounds__(DIM) void k_init(
    const float* __restrict__ x0, float* __restrict__ centers,
    unsigned short* __restrict__ cbfg, float* __restrict__ csqg)
{
    __shared__ float rowv[DIM];
    const int k = blockIdx.x, d = threadIdx.x;
    float v = x0[(size_t)k*DIM + d];
    centers[(size_t)k*DIM + d] = v;
    cbfg[(size_t)k*DIM + d] = bf16_rne(v);
    rowv[d] = v;
    __syncthreads();
    if (d == 0) csqg[k] = np_sumsq128(rowv, 1);
}

// ---------------- assignment: bf16-MFMA screen + exact np rescue (r11 exact) ----------------
__global__ __launch_bounds__(512, 1) void k_screen(
    const float* __restrict__ x0, const float* __restrict__ centers,
    const unsigned short* __restrict__ cbfg, const float* __restrict__ csqg,
    int* __restrict__ assignv)
{
    __shared__ float          xf[128][132];
    __shared__ unsigned short cbf[256][136];
    __shared__ float          csqL[K];
    __shared__ float          xsqL[128];
    __shared__ unsigned int   pcnt[128];
    __shared__ unsigned char  plist[128][CAPP];
    __shared__ unsigned int   smink[4][128];
    __shared__ unsigned char  sminn[4][128];

    const int tid = threadIdx.x, lane = tid & 63, w = tid >> 6;
    const int g = lane >> 4, fr = lane & 15;

    if (tid < 128) pcnt[tid] = 0u;

    {
        const uint4* c8p = (const uint4*)cbfg;
        #pragma unroll
        for (int i = 0; i < 8; ++i) {
            int idx = i*512 + tid;
            int row = idx >> 4, c8 = idx & 15;
            *(uint4*)&cbf[row][c8*8] = c8p[idx];
        }
    }
    {
        const float4* x4 = (const float4*)x0 + (size_t)blockIdx.x*128*32;
        #pragma unroll
        for (int i = 0; i < 8; ++i) {
            int idx = i*512 + tid;
            int row = idx >> 5, c4 = idx & 31;
            *(float4*)&xf[row][c4*4] = x4[idx];
        }
    }
    __syncthreads();

    if (tid < 256) csqL[tid] = csqg[tid];
    if (tid < 128) xsqL[tid] = np_sumsq128_f4(&xf[tid][0]);
    __syncthreads();

    bf16x8 ah[4];
    #pragma unroll
    for (int ks = 0; ks < 4; ++ks) {
        const float* xp = &xf[w*16 + fr][ks*32 + g*8];
        float4 a0 = *(const float4*)xp;
        float4 a1 = *(const float4*)(xp + 4);
        bf16x8 t;
        t[0] = (short)bf16_rne(a0.x); t[1] = (short)bf16_rne(a0.y);
        t[2] = (short)bf16_rne(a0.z); t[3] = (short)bf16_rne(a0.w);
        t[4] = (short)bf16_rne(a1.x); t[5] = (short)bf16_rne(a1.y);
        t[6] = (short)bf16_rne(a1.z); t[7] = (short)bf16_rne(a1.w);
        ah[ks] = t;
    }

    f32x4 acc[16];
    #pragma unroll
    for (int t = 0; t < 16; ++t) acc[t] = (f32x4){0.f, 0.f, 0.f, 0.f};
    #pragma unroll
    for (int t = 0; t < 16; ++t) {
        #pragma unroll
        for (int ks = 0; ks < 4; ++ks) {
            bf16x8 b = *(const bf16x8*)&cbf[t*16 + fr][ks*32 + g*8];
            acc[t] = __builtin_amdgcn_mfma_f32_16x16x32_bf16(ah[ks], b, acc[t], 0, 0, 0);
        }
    }

    float csqv[16];
    #pragma unroll
    for (int t = 0; t < 16; ++t) csqv[t] = csqL[t*16 + fr];

    float m1r[4];
    #pragma unroll
    for (int r = 0; r < 4; ++r) {
        float m = 1e30f;
        #pragma unroll
        for (int t = 0; t < 16; ++t) { float s = csqv[t] - 2.f*acc[t][r]; m = fminf(m, s); }
        #pragma unroll
        for (int off = 1; off < 16; off <<= 1) m = fminf(m, __shfl_xor(m, off));
        m1r[r] = m;
    }
    #pragma unroll
    for (int t = 0; t < 16; ++t)
        #pragma unroll
        for (int r = 0; r < 4; ++r) {
            float s = csqv[t] - 2.f*acc[t][r];
            if (s <= m1r[r] + WMARG) {
                int row = w*16 + g*4 + r;
                unsigned int slot = atomicAdd(&pcnt[row], 1u);
                if (slot < CAPP) plist[row][slot] = (unsigned char)(t*16 + fr);
            }
        }
    __syncthreads();

    // ---- exact np rescue: 4 threads per point (r11 single-chain, no unroll) ----
    {
        const int pt = tid & 127, q = tid >> 7;
        unsigned int ccnt = pcnt[pt];
        int cnt = (ccnt < (unsigned)CAPP) ? (int)ccnt : CAPP;
        unsigned int bkey = 0xFFFFFFFFu; int bn = 255;
        const float xs_ = xsqL[pt];
        const float* xp = &xf[pt][0];
        for (int i = q; i < cnt; i += 4) {
            int kk = plist[pt][i];
            const float* cp = &centers[(size_t)kk*DIM];
            float dot = 0.f;
            for (int d0 = 0; d0 < DIM; d0 += 16) {
                float4 c0 = *(const float4*)(cp + d0);
                float4 c1 = *(const float4*)(cp + d0 + 4);
                float4 c2 = *(const float4*)(cp + d0 + 8);
                float4 c3 = *(const float4*)(cp + d0 + 12);
                float4 xa = *(const float4*)(xp + d0);
                float4 xb = *(const float4*)(xp + d0 + 4);
                float4 xc = *(const float4*)(xp + d0 + 8);
                float4 xd = *(const float4*)(xp + d0 + 12);
                dot = fmaf(xa.x, c0.x, dot); dot = fmaf(xa.y, c0.y, dot);
                dot = fmaf(xa.z, c0.z, dot); dot = fmaf(xa.w, c0.w, dot);
                dot = fmaf(xb.x, c1.x, dot); dot = fmaf(xb.y, c1.y, dot);
                dot = fmaf(xb.z, c1.z, dot); dot = fmaf(xb.w, c1.w, dot);
                dot = fmaf(xc.x, c2.x, dot); dot = fmaf(xc.y, c2.y, dot);
                dot = fmaf(xc.z, c2.z, dot); dot = fmaf(xc.w, c2.w, dot);
                dot = fmaf(xd.x, c3.x, dot); dot = fmaf(xd.y, c3.y, dot);
                dot = fmaf(xd.z, c3.z, dot); dot = fmaf(xd.w, c3.w, dot);
            }
            float d2;
            {
                #pragma clang fp contract(off)
                float m = 2.f*dot;
                float t = xs_ + csqL[kk];
                d2 = t - m;
            }
            unsigned int b = __float_as_uint(d2);
            unsigned int key = (b & 0x80000000u) ? ~b : (b | 0x80000000u);
            if (key < bkey || (key == bkey && kk < bn)) { bkey = key; bn = kk; }
        }
        smink[q][pt] = bkey;
        sminn[q][pt] = (unsigned char)bn;
    }
    __syncthreads();
    if (tid < 128) {
        unsigned int Bk = smink[0][tid]; int Bn = sminn[0][tid];
        #pragma unroll
        for (int q = 1; q < 4; ++q) {
            unsigned int u = smink[q][tid]; int n = sminn[q][tid];
            if (u < Bk || (u == Bk && n < Bn)) { Bk = u; Bn = n; }
        }
        assignv[blockIdx.x*128 + tid] = Bn;   // first-min tie rule == np.argmin
    }
}

// ---------------- fused segment-sum + update + cbf/csq emit ----------------
// 512 threads: threads 0-127 = r11-proven scan/compact/fold (unchanged);
// threads 128-511 = one-shot L2 prefetch sweep over EVERY 128-B line of the
// cluster's rows (q enumerates lines: row=q>>2, line=q&3), ascending order so
// it runs ahead of the ascending-order folder.
#define LOADL(vv, t0) do {                                                  \
    int base_ = (t0)*FT;                                                    \
    int nn_[FT];                                                            \
    _Pragma("unroll")                                                       \
    for (int j = 0; j < FT; ++j) {                                          \
        int idx_ = base_ + j;                                               \
        nn_[j] = nlist[idx_ < L ? idx_ : 0];                                \
    }                                                                       \
    _Pragma("unroll")                                                       \
    for (int j = 0; j < FT; ++j) vv[j] = x0[(size_t)nn_[j]*DIM + d];        \
} while (0)

#define FOLDL(vv, t0) do {                                                  \
    int rem_ = L - (t0)*FT;                                                 \
    if (rem_ >= FT) {                                                       \
        _Pragma("unroll")                                                   \
        for (int j = 0; j < FT; ++j) s = s + vv[j];                         \
    } else if (rem_ > 0) {                                                  \
        _Pragma("unroll")                                                   \
        for (int j = 0; j < FT; ++j) { float t_ = s + vv[j]; s = (j < rem_) ? t_ : s; } \
    }                                                                       \
} while (0)

__global__ __launch_bounds__(512, 1) void k_seg(
    const float* __restrict__ x0, const int* __restrict__ assignv,
    float* __restrict__ centers, unsigned short* __restrict__ cbfg,
    float* __restrict__ csqg)
{
    __shared__ int nlist[NPTS];        // 128 KB
    __shared__ int tsum[2];
    __shared__ float rowv[DIM];
    const int k   = blockIdx.x;
    const int tid = threadIdx.x, lane = tid & 63, w = tid >> 6;

    // r11 scan (threads 0-127 only; each scans 256 pts = 64 int4)
    const int4* a4 = (const int4*)assignv;
    int cnt = 0, incl = 0;
    if (tid < 128) {
        for (int b = 0; b < 64; b += 8) {
            int4 v[8];
            #pragma unroll
            for (int j = 0; j < 8; ++j) v[j] = a4[tid*64 + b + j];
            #pragma unroll
            for (int j = 0; j < 8; ++j)
                cnt += (v[j].x == k) + (v[j].y == k) + (v[j].z == k) + (v[j].w == k);
        }
        incl = cnt;
        #pragma unroll
        for (int off = 1; off < 64; off <<= 1) {
            int o = __shfl_up(incl, off);
            if (lane >= off) incl += o;
        }
        if (lane == 63) tsum[w] = incl;
    }
    __syncthreads();
    const int L = tsum[0] + tsum[1];

    if (tid < 128) {
        int excl = incl - cnt + (w == 1 ? tsum[0] : 0);
        int wpos = excl;
        for (int b = 0; b < 64; b += 8) {
            int4 v[8];
            #pragma unroll
            for (int j = 0; j < 8; ++j) v[j] = a4[tid*64 + b + j];
            #pragma unroll
            for (int j = 0; j < 8; ++j) {
                int n0 = tid*256 + (b+j)*4;
                if (v[j].x == k) nlist[wpos++] = n0;
                if (v[j].y == k) nlist[wpos++] = n0+1;
                if (v[j].z == k) nlist[wpos++] = n0+2;
                if (v[j].w == k) nlist[wpos++] = n0+3;
            }
        }
    }
    __syncthreads();

    if (tid < 128) {
        const int d = tid;
        float nv;
        if (L > 0) {
            #pragma clang fp contract(off)
            float vA[FT], vB[FT];
            float s = 0.f;
            const int nt = (L + FT - 1) / FT;
            LOADL(vA, 0);
            for (int t = 0; t < nt; t += 2) {
                LOADL(vB, t+1);
                FOLDL(vA, t);
                LOADL(vA, t+2);
                FOLDL(vB, t+1);
            }
            float c = (float)L;
            nv = s / fmaxf(c, 1.f);                  // IEEE div == np
            centers[(size_t)k*DIM + d] = nv;         // write only if L>0 (np.where)
        } else {
            nv = centers[(size_t)k*DIM + d];
        }
        cbfg[(size_t)k*DIM + d] = bf16_rne(nv);
        rowv[d] = nv;
    } else if (L > 512) {
        // prefetch: all 4 lines of every row, ascending, batched 8 for MLP
        const int i = tid - 128;                 // 0..383
        const int QT = L * 4;                    // total 128B lines
        for (int base = i*8; base < QT; base += 384*8) {
            float vk[8];
            #pragma unroll
            for (int j = 0; j < 8; ++j) {
                int q = base + j;
                q = (q < QT) ? q : 0;
                int nn = nlist[q >> 2];
                vk[j] = x0[(size_t)nn*DIM + (q & 3)*32];
            }
            #pragma unroll
            for (int j = 0; j < 8; ++j) asm volatile("" :: "v"(vk[j]));
        }
    }
    __syncthreads();
    if (tid == 0) csqg[k] = np_sumsq128(rowv, 1);
}

// ---------------- M = W @ centers / 128 (fp32), split to bf16 hi/lo ----------------
__global__ void k_makeM(const float* __restrict__ W, const float* __restrict__ centers,
                        unsigned short* __restrict__ Mh, unsigned short* __restrict__ Ml,
                        float* __restrict__ out_centers)
{
    int k = blockIdx.x, d = threadIdx.x;
    float s = 0.f;
    #pragma unroll 8
    for (int i = 0; i < K; ++i) s = fmaf(W[k*K + i], centers[i*DIM + d], s);
    s *= (1.f/128.f);
    unsigned short h = bf16_rne(s);
    float lo = s - bf16_to_f(h);
    unsigned short l2 = bf16_rne(lo);
    Mh[k*DIM + d] = h;
    Ml[k*DIM + d] = l2;
    out_centers[k*DIM + d] = centers[k*DIM + d];
}

// ---------------- out = X @ M^T via bf16-split MFMA (proven r8) ----------------
__global__ __launch_bounds__(256, 2) void k_out_mfma(
    const float* __restrict__ x, const unsigned short* __restrict__ Mh,
    const unsigned short* __restrict__ Ml, float* __restrict__ outp)
{
    __shared__ unsigned short AhL[32][DIM+8];
    __shared__ unsigned short AlL[32][DIM+8];

    const int tid = threadIdx.x, lane = tid & 63, w = tid >> 6;

    bf16x8 bh[4][4], bl[4][4];
    #pragma unroll
    for (int tt = 0; tt < 4; ++tt)
        #pragma unroll
        for (int s = 0; s < 4; ++s) {
            int col = (w*4 + tt)*16 + (lane & 15);
            int off = col*DIM + 32*s + (lane >> 4)*8;
            bh[tt][s] = *(const bf16x8*)&Mh[off];
            bl[tt][s] = *(const bf16x8*)&Ml[off];
        }

    for (int strip = blockIdx.x; strip < NALL/32; strip += gridDim.x) {
        const int sbase = strip * 32;
        __syncthreads();
        const float4* x4 = (const float4*)x;
        #pragma unroll
        for (int i = 0; i < 4; ++i) {
            int idx = i*256 + tid;
            int row = idx >> 5, c4 = idx & 31;
            float4 v = x4[(size_t)(sbase + row)*32 + c4];
            ushort4 hh, ll;
            float f; unsigned short h;
            f = v.x; h = bf16_rne(f); hh.x = h; ll.x = bf16_rne(f - bf16_to_f(h));
            f = v.y; h = bf16_rne(f); hh.y = h; ll.y = bf16_rne(f - bf16_to_f(h));
            f = v.z; h = bf16_rne(f); hh.z = h; ll.z = bf16_rne(f - bf16_to_f(h));
            f = v.w; h = bf16_rne(f); hh.w = h; ll.w = bf16_rne(f - bf16_to_f(h));
            *(ushort4*)&AhL[row][c4*4] = hh;
            *(ushort4*)&AlL[row][c4*4] = ll;
        }
        __syncthreads();

        f32x4 acc[2][4];
        #pragma unroll
        for (int rt = 0; rt < 2; ++rt)
            #pragma unroll
            for (int tt = 0; tt < 4; ++tt)
                acc[rt][tt] = (f32x4){0.f, 0.f, 0.f, 0.f};

        #pragma unroll
        for (int s = 0; s < 4; ++s) {
            bf16x8 ah[2], al[2];
            #pragma unroll
            for (int rt = 0; rt < 2; ++rt) {
                int r = (lane & 15) + 16*rt;
                int kc = 32*s + (lane >> 4)*8;
                ah[rt] = *(const bf16x8*)&AhL[r][kc];
                al[rt] = *(const bf16x8*)&AlL[r][kc];
            }
            #pragma unroll
            for (int rt = 0; rt < 2; ++rt)
                #pragma unroll
                for (int tt = 0; tt < 4; ++tt) {
                    acc[rt][tt] = __builtin_amdgcn_mfma_f32_16x16x32_bf16(ah[rt], bh[tt][s], acc[rt][tt], 0, 0, 0);
                    acc[rt][tt] = __builtin_amdgcn_mfma_f32_16x16x32_bf16(ah[rt], bl[tt][s], acc[rt][tt], 0, 0, 0);
                    acc[rt][tt] = __builtin_amdgcn_mfma_f32_16x16x32_bf16(al[rt], bh[tt][s], acc[rt][tt], 0, 0, 0);
                }
        }

        #pragma unroll
        for (int rt = 0; rt < 2; ++rt)
            #pragma unroll
            for (int tt = 0; tt < 4; ++tt)
                #pragma unroll
                for (int reg = 0; reg < 4; ++reg) {
                    int row = sbase + rt*16 + (lane >> 4)*4 + reg;
                    int col = w*64 + tt*16 + (lane & 15);
                    outp[(size_t)row*K + col] = acc[rt][tt][reg];
                }
    }
}

extern "C" void kernel_launch(void* const* d_in, const int* in_sizes, int n_in,
                              void* d_out, int out_size, void* d_ws, size_t ws_size,
                              hipStream_t stream)
{
    const float* x = (const float*)d_in[0];   // [8][32768][128]
    const float* W = (const float*)d_in[1];   // [256][256]
    float* outp        = (float*)d_out;                       // [262144][256]
    float* out_centers = outp + (size_t)NALL * K;             // [256][128]

    // workspace layout (4B units)
    float* ws       = (float*)d_ws;
    float* centers  = ws;                                 // 32768
    int*   assignv  = (int*)(ws + 32768);                 // 32768
    unsigned short* Mh = (unsigned short*)(ws + 65536);   // 32768 ushort
    unsigned short* Ml = (unsigned short*)(ws + 81920);   // 32768 ushort
    unsigned short* cbfg = (unsigned short*)(ws + 98304); // 32768 ushort
    float* csqg     = ws + 114688;                        // 256
    (void)ws_size;

    k_init<<<K, DIM, 0, stream>>>(x, centers, cbfg, csqg);
    for (int it = 0; it < ITERS; ++it) {
        k_screen<<<NPTS/128, 512, 0, stream>>>(x, centers, cbfg, csqg, assignv);
        k_seg   <<<K, 512, 0, stream>>>(x, assignv, centers, cbfg, csqg);
    }
    k_makeM<<<K, DIM, 0, stream>>>(W, centers, Mh, Ml, out_centers);
    k_out_mfma<<<2048, 256, 0, stream>>>(x, Mh, Ml, outp);
}